// Round 8
// baseline (228.405 us; speedup 1.0000x reference)
//
#include <hip/hip_runtime.h>
#include <hip/hip_bf16.h>

#define B_ 4
#define U_ 16
#define L_ 128
#define H_ 768
#define M_ 256
#define HID_ 150

typedef _Float16 half8 __attribute__((ext_vector_type(8)));
typedef _Float16 half4t __attribute__((ext_vector_type(4)));
typedef float floatx4 __attribute__((ext_vector_type(4)));
typedef float floatx16 __attribute__((ext_vector_type(16)));

#define MFMA32(wf, af, acc) __builtin_amdgcn_mfma_f32_32x32x16_f16(wf, af, acc, 0, 0, 0)

// ---------------------------------------------------------------------------
// Kernel 0: fused prep (blocks 0..1539) + pool (blocks 1540..1795).
// prep: coalesced weight prepack (formats HW-verified R6/R7, absmax 0).
// pool: masked mean-pool -> f16, 4 rows/block, 64 thr/row.
// ---------------------------------------------------------------------------
__global__ __launch_bounds__(256) void prep_pool_kernel(
    const float* __restrict__ W1, const float* __restrict__ W2,
    const float* __restrict__ b2, const float* __restrict__ W3,
    const float* __restrict__ hidden, const int* __restrict__ sutt,
    const int* __restrict__ sstart, const int* __restrict__ send,
    _Float16* __restrict__ W1cs, _Float16* __restrict__ W2s,
    _Float16* __restrict__ W1abs, float2* __restrict__ bw,
    _Float16* __restrict__ pooledh)
{
    if (blockIdx.x >= 1540) {   // ---- pool part ----
        const int bm = (blockIdx.x - 1540) * 4 + (threadIdx.x >> 6);
        const int lane = threadIdx.x & 63;
        const int b  = bm >> 8;
        const int u  = sutt[bm];
        const int st = sstart[bm];
        const int en = send[bm];
        const float inv = 1.0f / (float)(en - st);
        const float* src = hidden + ((size_t)(b * U_ + u) * L_) * H_ + lane * 12;
        float4 s[3];
        #pragma unroll
        for (int q = 0; q < 3; ++q) s[q] = make_float4(0.f, 0.f, 0.f, 0.f);
        for (int l = st; l < en; ++l) {
            const float* p = src + (size_t)l * H_;
            #pragma unroll
            for (int q = 0; q < 3; ++q) {
                float4 v = *(const float4*)(p + q * 4);
                s[q].x += v.x; s[q].y += v.y; s[q].z += v.z; s[q].w += v.w;
            }
        }
        _Float16* gp = pooledh + (size_t)bm * H_ + lane * 12;
        #pragma unroll
        for (int q = 0; q < 3; ++q) {
            half4t hv;
            hv[0] = (_Float16)(s[q].x * inv); hv[1] = (_Float16)(s[q].y * inv);
            hv[2] = (_Float16)(s[q].z * inv); hv[3] = (_Float16)(s[q].w * inv);
            *(half4t*)(gp + q * 4) = hv;
        }
        return;
    }
    // ---- prep part ----
    int idx = blockIdx.x * 256 + threadIdx.x;
    if (blockIdx.x == 0 && threadIdx.x < 160) {
        int n = threadIdx.x;
        bw[n] = (n < HID_) ? make_float2(b2[n], W3[n]) : make_float2(0.f, 0.f);
    }
    if (idx < 122880) {   // W1cs: idx = k*160 + n
        int k = idx / 160, n = idx - k * 160;
        float v = (n < HID_) ? W1[(size_t)(2 * H_ + k) * HID_ + n] : 0.f;
        W1cs[(k >> 4) * 2560 + (n >> 5) * 512 +
             (((n & 31) | (((k >> 3) & 1) << 5)) << 3) + (k & 7)] = (_Float16)v;
        return;
    }
    idx -= 122880;
    if (idx < 25600) {    // W2s
        int k = idx / 160, n = idx - k * 160;
        float v = (k < HID_ && n < HID_) ? W2[(size_t)k * HID_ + n] : 0.f;
        W2s[(k >> 4) * 2560 + (n >> 5) * 512 +
            (((n & 31) | (((k >> 3) & 1) << 5)) << 3) + (k & 7)] = (_Float16)v;
        return;
    }
    idx -= 25600;
    if (idx < 245760) {   // W1abs
        int k = idx / 320, n = idx - k * 320;
        float v = 0.f;
        if (n < HID_) v = W1[(size_t)k * HID_ + n];
        else if (n >= 160 && n < 160 + HID_) v = W1[(size_t)(H_ + k) * HID_ + (n - 160)];
        W1abs[(k >> 5) * 10240 + (n >> 4) * 512 +
              (((n & 15) | (((k >> 3) & 3) << 4)) << 3) + (k & 7)] = (_Float16)v;
    }
}

// ---------------------------------------------------------------------------
// Kernel 1: hi/hj projection (also zeroes the output scalar for loss).
// 64 blocks x 16 rows, 16x16x32 MFMA vs W1abs.
// ---------------------------------------------------------------------------
__global__ __launch_bounds__(256) void hihj_kernel(
    const _Float16* __restrict__ pooledh, const float* __restrict__ b1,
    const _Float16* __restrict__ W1abs,
    float* __restrict__ hiF, float* __restrict__ hjT, float* __restrict__ out)
{
    if (blockIdx.x == 0 && threadIdx.x == 0) *out = 0.f;   // replaces memset
    __shared__ __align__(16) _Float16 spool[16 * 776];
    const int blk = blockIdx.x;
    const int tid = threadIdx.x;
    for (int e = tid; e < 16 * 96; e += 256) {
        int r = e / 96, c = e - r * 96;
        *(half8*)&spool[r * 776 + c * 8] =
            *(const half8*)&pooledh[(size_t)(blk * 16 + r) * H_ + c * 8];
    }
    __syncthreads();

    const int w = tid >> 6, lane = tid & 63;
    const int g = lane >> 4, l15 = lane & 15;
    floatx4 acc[5];
    #pragma unroll
    for (int u5 = 0; u5 < 5; ++u5) acc[u5] = (floatx4){0.f, 0.f, 0.f, 0.f};
    const _Float16* aB = &spool[l15 * 776 + g * 8];
    for (int kc = 0; kc < 24; ++kc) {
        half8 av = *(const half8*)(aB + kc * 32);
        #pragma unroll
        for (int u5 = 0; u5 < 5; ++u5) {
            const int u = w * 5 + u5;
            half8 bv = *(const half8*)(W1abs + (size_t)((kc * 20 + u) * 64 + lane) * 8);
            acc[u5] = __builtin_amdgcn_mfma_f32_16x16x32_f16(av, bv, acc[u5], 0, 0, 0);
        }
    }
    const int row0 = blk * 16 + g * 4;
    #pragma unroll
    for (int u5 = 0; u5 < 5; ++u5) {
        const int n = (w * 5 + u5) * 16 + l15;
        if (n < HID_) {
            float b1v = b1[n];
            #pragma unroll
            for (int r = 0; r < 4; ++r)
                hiF[(size_t)(row0 + r) * 160 + n] = acc[u5][r] + b1v;
        } else if (n >= 160 && n < 160 + HID_) {
            *(float4*)&hjT[(size_t)(n - 160) * 1024 + row0] =
                make_float4(acc[u5][0], acc[u5][1], acc[u5][2], acc[u5][3]);
        }
    }
}

// ---------------------------------------------------------------------------
// Kernel 2: fused pair MLP. R6 sharing structure at (256,1) — no spills
// (R6 lesson: 372 unified regs never fit 2 waves/SIMD; 1 wave/SIMD + LDS
// weight sharing is the design point).
// Block = 4 waves; wave w -> i-pair p = 16*jt + 4*t + w, tiles (2p, 2p+1) x
// 32 j. Stage1: W1c in LDS dbuf, 64-K super-chunks (12 barriers); A-gathers
// prefetched 1 super-chunk ahead, fully unrolled (const-folded [sc&1] bufs,
// no copies -> no per-iter vmcnt(0) drain — the R7 failure mode).
// h1 (both tiles) -> wave-private LDS, no barrier. Stage2 merged over tiles
// (halves W2 L2 traffic), 3-deep W2 rotation. LDS 40+85=125 KB, 1 block/CU.
// C/D 32x32: col=lane&31, row=(reg&3)+8*(reg>>2)+4*(lane>>5).  [R4-verified]
// ---------------------------------------------------------------------------
__global__ __launch_bounds__(256, 1) void pair_mlp_kernel(
    const _Float16* __restrict__ pooledh,
    const float* __restrict__ hiF, const float* __restrict__ hjT,
    const _Float16* __restrict__ W1cs, const _Float16* __restrict__ W2s,
    const float2* __restrict__ bw, const float* __restrict__ b3,
    float* __restrict__ logits)
{
    __shared__ __align__(16) _Float16 sW[2][10240];      // 40 KB, 64-K dbuf
    __shared__ __align__(16) _Float16 h1L[4][64 * 170];  // 85 KB wave-private

    const int b = blockIdx.y;
    int t = blockIdx.x;                  // 0..143
    int jt = 0;
    while (t >= 32 - 4 * jt) { t -= 32 - 4 * jt; ++jt; }
    const int tid = threadIdx.x;
    const int w = tid >> 6, lane = tid & 63;
    const int p = 16 * jt + 4 * t + w;   // i-pair
    const int i0 = 2 * p, j0 = 32 * jt;
    const int bm = b * M_;
    const int c31 = lane & 31, hw = lane >> 5;

    const _Float16* pjp  = pooledh + (size_t)(bm + j0 + c31) * H_ + (hw << 3);
    const _Float16* pip0 = pooledh + (size_t)(bm + i0) * H_ + (hw << 3);
    const _Float16* pip1 = pooledh + (size_t)(bm + i0 + 1) * H_ + (hw << 3);

    floatx16 acc1[2][5];
    #pragma unroll
    for (int tt = 0; tt < 2; ++tt)
        #pragma unroll
        for (int t1 = 0; t1 < 5; ++t1)
            #pragma unroll
            for (int e = 0; e < 16; ++e) acc1[tt][t1][e] = 0.f;

    half8 Apj[2][4], Ai0[2][4], Ai1[2][4], stg[2][5];

    // ---- prologue: super-chunk 0 ----
    #pragma unroll
    for (int q = 0; q < 5; ++q)
        stg[0][q] = *(const half8*)(W1cs + (size_t)(tid + q * 256) * 8);
    #pragma unroll
    for (int h = 0; h < 4; ++h) {
        Apj[0][h] = *(const half8*)(pjp + h * 16);
        Ai0[0][h] = *(const half8*)(pip0 + h * 16);
        Ai1[0][h] = *(const half8*)(pip1 + h * 16);
    }
    #pragma unroll
    for (int q = 0; q < 5; ++q)
        *(half8*)&sW[0][(tid + q * 256) * 8] = stg[0][q];
    __syncthreads();

    // ---- stage 1: 12 super-chunks of K=64, fully unrolled ----
    #pragma unroll
    for (int sc = 0; sc < 12; ++sc) {
        const int cur = sc & 1, nxt = cur ^ 1;
        if (sc < 11) {
            const _Float16* wg = W1cs + (size_t)(sc + 1) * 10240;
            #pragma unroll
            for (int q = 0; q < 5; ++q)
                stg[nxt][q] = *(const half8*)(wg + (size_t)(tid + q * 256) * 8);
            const int kb = (sc + 1) * 64;
            #pragma unroll
            for (int h = 0; h < 4; ++h) {
                Apj[nxt][h] = *(const half8*)(pjp + kb + h * 16);
                Ai0[nxt][h] = *(const half8*)(pip0 + kb + h * 16);
                Ai1[nxt][h] = *(const half8*)(pip1 + kb + h * 16);
            }
        }
        #pragma unroll
        for (int h = 0; h < 4; ++h) {
            half8 a0 = Ai0[cur][h] * Apj[cur][h];
            half8 a1 = Ai1[cur][h] * Apj[cur][h];
            #pragma unroll
            for (int t1 = 0; t1 < 5; ++t1) {
                half8 wf = *(const half8*)&sW[cur][h * 2560 + t1 * 512 + lane * 8];
                acc1[0][t1] = MFMA32(wf, a0, acc1[0][t1]);
                acc1[1][t1] = MFMA32(wf, a1, acc1[1][t1]);
            }
        }
        if (sc < 11) {
            #pragma unroll
            for (int q = 0; q < 5; ++q)
                *(half8*)&sW[nxt][(tid + q * 256) * 8] = stg[nxt][q];
            __syncthreads();
        }
    }

    // ---- epilogue 1: h1 = relu(acc1 + hiF + hjT) for BOTH tiles -> LDS ----
    _Float16* h1w = h1L[w];
    #pragma unroll
    for (int t1 = 0; t1 < 5; ++t1) {
        #pragma unroll
        for (int qd = 0; qd < 4; ++qd) {
            const int n1 = t1 * 32 + 8 * qd + 4 * hw;
            float hj0 = hjT[(size_t)(n1 + 0) * 1024 + bm + j0 + c31];
            float hj1 = hjT[(size_t)(n1 + 1) * 1024 + bm + j0 + c31];
            float hj2 = hjT[(size_t)(n1 + 2) * 1024 + bm + j0 + c31];
            float hj3 = hjT[(size_t)(n1 + 3) * 1024 + bm + j0 + c31];
            #pragma unroll
            for (int tt = 0; tt < 2; ++tt) {
                float4 hiv = *(const float4*)&hiF[(size_t)(bm + i0 + tt) * 160 + n1];
                half4t hv;
                hv[0] = (_Float16)fmaxf(acc1[tt][t1][4 * qd + 0] + hiv.x + hj0, 0.f);
                hv[1] = (_Float16)fmaxf(acc1[tt][t1][4 * qd + 1] + hiv.y + hj1, 0.f);
                hv[2] = (_Float16)fmaxf(acc1[tt][t1][4 * qd + 2] + hiv.z + hj2, 0.f);
                hv[3] = (_Float16)fmaxf(acc1[tt][t1][4 * qd + 3] + hiv.w + hj3, 0.f);
                *(half4t*)&h1w[(tt * 32 + c31) * 170 + n1] = hv;
            }
        }
    }
    // wave-private region: same-wave ds ordering via lgkmcnt, no barrier.

    // ---- stage 2: h2^T = W2^T @ h1^T, both tiles share weight frags ----
    floatx16 acc2[2][5];
    #pragma unroll
    for (int tt = 0; tt < 2; ++tt)
        #pragma unroll
        for (int t2 = 0; t2 < 5; ++t2)
            #pragma unroll
            for (int e = 0; e < 16; ++e) acc2[tt][t2][e] = 0.f;

    half8 W2f[3][5];
    #pragma unroll
    for (int c = 0; c < 3; ++c) {
        const _Float16* wb = W2s + (size_t)(c * 5) * 512 + lane * 8;
        #pragma unroll
        for (int t2 = 0; t2 < 5; ++t2) W2f[c][t2] = *(const half8*)(wb + t2 * 512);
    }
    #pragma unroll
    for (int kc2 = 0; kc2 < 10; ++kc2) {
        const int cur = kc2 % 3;
        half8 h0 = *(const half8*)&h1w[c31 * 170 + kc2 * 16 + hw * 8];
        half8 h1f = *(const half8*)&h1w[(32 + c31) * 170 + kc2 * 16 + hw * 8];
        #pragma unroll
        for (int t2 = 0; t2 < 5; ++t2) {
            acc2[0][t2] = MFMA32(W2f[cur][t2], h0, acc2[0][t2]);
            acc2[1][t2] = MFMA32(W2f[cur][t2], h1f, acc2[1][t2]);
        }
        if (kc2 < 7) {
            const _Float16* wb = W2s + (size_t)((kc2 + 3) * 5) * 512 + lane * 8;
            #pragma unroll
            for (int t2 = 0; t2 < 5; ++t2)
                W2f[cur][t2] = *(const half8*)(wb + t2 * 512);
        }
    }

    // ---- stage 3: s = relu(h2^T + b2).W3 + b3 -> logits ----
    const float b3v = b3[0];
    #pragma unroll
    for (int tt = 0; tt < 2; ++tt) {
        float sown = 0.f;
        #pragma unroll
        for (int t2 = 0; t2 < 5; ++t2) {
            #pragma unroll
            for (int qd = 0; qd < 4; ++qd) {
                const int n2 = t2 * 32 + 8 * qd + 4 * hw;
                float4 bw01 = *(const float4*)&bw[n2];
                float4 bw23 = *(const float4*)&bw[n2 + 2];
                sown += fmaxf(acc2[tt][t2][4 * qd + 0] + bw01.x, 0.f) * bw01.y;
                sown += fmaxf(acc2[tt][t2][4 * qd + 1] + bw01.z, 0.f) * bw01.w;
                sown += fmaxf(acc2[tt][t2][4 * qd + 2] + bw23.x, 0.f) * bw23.y;
                sown += fmaxf(acc2[tt][t2][4 * qd + 3] + bw23.z, 0.f) * bw23.w;
            }
        }
        float s = sown + __shfl_xor(sown, 32);
        const int i = i0 + tt;
        const int j = j0 + c31;
        if (lane < 32 && j < i)
            logits[(size_t)(bm + i) * M_ + j] = s + b3v;
    }
}

// ---------------------------------------------------------------------------
// Kernel 3: per-row softmax over j<=i, clipped label-mass NLL, atomic sum.
// ---------------------------------------------------------------------------
__global__ __launch_bounds__(256) void loss_kernel(
    const float* __restrict__ logits, const float* __restrict__ labels,
    float* __restrict__ out)
{
    const int bm = blockIdx.x;
    const int i  = bm & (M_ - 1);
    const int j  = threadIdx.x;
    __shared__ float red[4];
    __shared__ float bcast;

    float val = (j < i) ? logits[(size_t)bm * M_ + j]
                        : ((j == i) ? 0.0f : -1e30f);

    float m = val;
    #pragma unroll
    for (int off = 32; off >= 1; off >>= 1) m = fmaxf(m, __shfl_down(m, off, 64));
    const int wave = j >> 6, lane = j & 63;
    if (lane == 0) red[wave] = m;
    __syncthreads();
    if (j == 0) bcast = fmaxf(fmaxf(red[0], red[1]), fmaxf(red[2], red[3]));
    __syncthreads();
    const float mm = bcast;

    float e = (j <= i) ? expf(val - mm) : 0.0f;
    float s = e;
    #pragma unroll
    for (int off = 32; off >= 1; off >>= 1) s += __shfl_down(s, off, 64);
    __syncthreads();
    if (lane == 0) red[wave] = s;
    __syncthreads();
    if (j == 0) bcast = red[0] + red[1] + red[2] + red[3];
    __syncthreads();
    const float ssum = bcast;

    float prob = (j <= i) ? (e / ssum) : -1000.0f;
    float lab = labels[(size_t)bm * M_ + j];
    float tv = prob * lab;
    tv = fminf(fmaxf(tv, 1e-8f), 1.0f - 1e-8f);
    float rs = tv;
    #pragma unroll
    for (int off = 32; off >= 1; off >>= 1) rs += __shfl_down(rs, off, 64);
    __syncthreads();
    if (lane == 0) red[wave] = rs;
    __syncthreads();
    if (j == 0) atomicAdd(out, -logf(red[0] + red[1] + red[2] + red[3]));
}

// ---------------------------------------------------------------------------
extern "C" void kernel_launch(void* const* d_in, const int* in_sizes, int n_in,
                              void* d_out, int out_size, void* d_ws, size_t ws_size,
                              hipStream_t stream)
{
    const float* hidden = (const float*)d_in[0];
    const int*   sutt   = (const int*)d_in[1];
    const int*   sstart = (const int*)d_in[2];
    const int*   send   = (const int*)d_in[3];
    const float* labels = (const float*)d_in[4];
    const float* W1     = (const float*)d_in[5];
    const float* b1     = (const float*)d_in[6];
    const float* W2     = (const float*)d_in[7];
    const float* b2     = (const float*)d_in[8];
    const float* W3     = (const float*)d_in[9];
    const float* b3     = (const float*)d_in[10];

    float* ws = (float*)d_ws;
    float*    hiF     = ws;                          // [1024][160]
    float*    hjT     = ws + 163840;                 // [160][1024]
    float*    logits  = ws + 327680;                 // 262144
    float2*   bw      = (float2*)(ws + 589824);      // 160 float2
    _Float16* pooledh = (_Float16*)(ws + 590144);    // 786432 f16
    _Float16* W1cs    = (_Float16*)(ws + 983360);    // 122880 f16
    _Float16* W2s     = (_Float16*)(ws + 1106240);   // 25600 f16
    _Float16* W1abs   = (_Float16*)(ws + 1119040);   // 245760 f16
    float* out = (float*)d_out;

    prep_pool_kernel<<<dim3(1796), 256, 0, stream>>>(
        W1, W2, b2, W3, hidden, sutt, sstart, send,
        W1cs, W2s, W1abs, bw, pooledh);
    hihj_kernel<<<dim3(64), 256, 0, stream>>>(pooledh, b1, W1abs, hiF, hjT, out);
    pair_mlp_kernel<<<dim3(144, B_), 256, 0, stream>>>(pooledh, hiF, hjT,
                                                       W1cs, W2s, bw, b3, logits);
    loss_kernel<<<dim3(B_ * M_), 256, 0, stream>>>(logits, labels, out);
}